// Round 1
// baseline (79.979 us; speedup 1.0000x reference)
//
#include <hip/hip_runtime.h>

#define TOTAL 286
#define KG 32      // grid points per Euler angle
#define LB 6       // bandwidth
#define NM 11      // 2L-1
#define CIN 16
#define COUT 32
#define BB 8

// One block per (b, o). 256 threads (4 waves).
__global__ __launch_bounds__(256) void so3_invconv_kernel(
    const float* __restrict__ x,    // [B, CIN, TOTAL]
    const float* __restrict__ w,    // [COUT, CIN, TOTAL]
    const float* __restrict__ d1,   // [KG, TOTAL]
    const float* __restrict__ d2,   // [KG, TOTAL]
    const float* __restrict__ ca1,  // [NM, KG]
    const float* __restrict__ cg1,  // [NM, KG]
    const float* __restrict__ ca2,  // [NM, KG]
    const float* __restrict__ cg2,  // [NM, KG]
    float* __restrict__ out)        // [B, COUT]
{
    __shared__ float ySm[TOTAL];
    __shared__ float s1[NM][NM], s2[NM][NM];
    __shared__ float t1[NM][KG], t2[NM][KG];
    __shared__ float ca1s[NM][KG], cg1s[NM][KG], ca2s[NM][KG], cg2s[NM][KG];
    __shared__ float red[256];

    const int tid = threadIdx.x;
    const int bid = blockIdx.x;        // = b*COUT + o
    const int b = bid >> 5;
    const int o = bid & 31;

    // Stage trig tables (11*32 = 352 floats each) into LDS.
    for (int e = tid; e < NM * KG; e += 256) {
        ((float*)ca1s)[e] = ca1[e];
        ((float*)cg1s)[e] = cg1[e];
        ((float*)ca2s)[e] = ca2[e];
        ((float*)cg2s)[e] = cg2[e];
    }

    // y[i] = sum_c x[b,c,i] * w[o,c,i]
    for (int i = tid; i < TOTAL; i += 256) {
        const float* xp = x + (size_t)b * CIN * TOTAL + i;
        const float* wp = w + (size_t)o * CIN * TOTAL + i;
        float acc = 0.f;
        #pragma unroll
        for (int c = 0; c < CIN; ++c)
            acc = fmaf(xp[c * TOTAL], wp[c * TOTAL], acc);
        ySm[i] = acc;
    }
    __syncthreads();

    float lmax = -INFINITY;

    // Per-thread (m,n) assignment for stage A (valid when tid < 121)
    const int mm = tid / NM;
    const int nn = tid - mm * NM;

    for (int q = 0; q < KG; ++q) {
        // ---- Stage A: S1[m,n] = sum_l y[i(l,m,n)] * d1[q,i], S2 likewise
        if (tid < NM * NM) {
            const int mp = mm - (LB - 1);
            const int np_ = nn - (LB - 1);
            const int am = mp < 0 ? -mp : mp;
            const int an = np_ < 0 ? -np_ : np_;
            const int lmin = am > an ? am : an;
            const float* d1q = d1 + q * TOTAL;
            const float* d2q = d2 + q * TOTAL;
            float a1 = 0.f, a2 = 0.f;
            for (int l = lmin; l < LB; ++l) {
                const int i = l * (4 * l * l - 1) / 3 + (2 * l + 1) * (l + mp) + (l + np_);
                const float yv = ySm[i];
                a1 = fmaf(yv, d1q[i], a1);
                a2 = fmaf(yv, d2q[i], a2);
            }
            s1[mm][nn] = a1;
            s2[mm][nn] = a2;
        }
        __syncthreads();

        // ---- Stage B: T1[m,r] = sum_n S1[m,n]*cg1[n,r]; T2 likewise (704 entries)
        for (int e = tid; e < 2 * NM * KG; e += 256) {
            const int which = (e >= NM * KG);
            const int ee = which ? e - NM * KG : e;
            const int m = ee >> 5;
            const int r = ee & 31;
            float acc = 0.f;
            if (!which) {
                #pragma unroll
                for (int n = 0; n < NM; ++n)
                    acc = fmaf(s1[m][n], cg1s[n][r], acc);
                t1[m][r] = acc;
            } else {
                #pragma unroll
                for (int n = 0; n < NM; ++n)
                    acc = fmaf(s2[m][n], cg2s[n][r], acc);
                t2[m][r] = acc;
            }
        }
        __syncthreads();

        // ---- Stage C: resp[p,r] = sum_m ca1[m,p]*T1[m,r] + ca2[m,p]*T2[m,r]; running max
        #pragma unroll
        for (int j = 0; j < 4; ++j) {
            const int e = tid + j * 256;
            const int p = e >> 5;
            const int r = e & 31;
            float acc = 0.f;
            #pragma unroll
            for (int m = 0; m < NM; ++m) {
                acc = fmaf(ca1s[m][p], t1[m][r], acc);
                acc = fmaf(ca2s[m][p], t2[m][r], acc);
            }
            lmax = fmaxf(lmax, acc);
        }
        __syncthreads();   // protect s/t buffers before next q overwrites
    }

    // ---- Block max reduction
    red[tid] = lmax;
    __syncthreads();
    #pragma unroll
    for (int s = 128; s > 0; s >>= 1) {
        if (tid < s) red[tid] = fmaxf(red[tid], red[tid + s]);
        __syncthreads();
    }
    if (tid == 0) out[bid] = red[0];
}

extern "C" void kernel_launch(void* const* d_in, const int* in_sizes, int n_in,
                              void* d_out, int out_size, void* d_ws, size_t ws_size,
                              hipStream_t stream) {
    const float* x   = (const float*)d_in[0];
    const float* w   = (const float*)d_in[1];
    const float* d1  = (const float*)d_in[2];
    const float* d2  = (const float*)d_in[3];
    const float* ca1 = (const float*)d_in[4];
    const float* cg1 = (const float*)d_in[5];
    const float* ca2 = (const float*)d_in[6];
    const float* cg2 = (const float*)d_in[7];
    // m_idx (d_in[8]) / n_idx (d_in[9]) not needed: indices computed analytically.

    so3_invconv_kernel<<<BB * COUT, 256, 0, stream>>>(
        x, w, d1, d2, ca1, cg1, ca2, cg2, (float*)d_out);
}

// Round 2
// 21.038 us; speedup vs baseline: 3.8017x; 3.8017x over previous
//
#include <hip/hip_runtime.h>

#define TOTAL 286
#define KG 32      // grid points per Euler angle
#define LB 6       // bandwidth
#define NM 11      // 2L-1
#define CIN 16
#define COUT 32
#define BB 8
#define QC 4       // q-chunks per (b,o)
#define QPB 8      // q per block == waves per block

typedef float v4 __attribute__((ext_vector_type(4)));

// Grid: B*COUT*QC = 1024 blocks, 512 threads (8 waves). Wave w handles q = qc*8 + w.
__global__ __launch_bounds__(512) void so3_main(
    const float* __restrict__ x,    // [B, CIN, TOTAL]
    const float* __restrict__ w,    // [COUT, CIN, TOTAL]
    const float* __restrict__ d1,   // [KG, TOTAL]
    const float* __restrict__ d2,   // [KG, TOTAL]
    const float* __restrict__ ca1,  // [NM, KG]
    const float* __restrict__ cg1,  // [NM, KG]
    const float* __restrict__ ca2,  // [NM, KG]
    const float* __restrict__ cg2,  // [NM, KG]
    float* __restrict__ partial)    // [B*COUT*QC]
{
    __shared__ __align__(16) float ca1s[NM][KG];
    __shared__ __align__(16) float cg1s[NM][KG];
    __shared__ __align__(16) float ca2s[NM][KG];
    __shared__ __align__(16) float cg2s[NM][KG];
    __shared__ __align__(16) float ySm[288];
    __shared__ float s1w[QPB][NM * NM];
    __shared__ float s2w[QPB][NM * NM];
    __shared__ __align__(16) float t1w[QPB][NM][KG];
    __shared__ __align__(16) float t2w[QPB][NM][KG];
    __shared__ float redw[QPB];

    const int tid  = threadIdx.x;
    const int lane = tid & 63;
    const int wid  = tid >> 6;
    const int bid  = blockIdx.x;
    const int qc   = bid & (QC - 1);
    const int bo   = bid >> 2;          // b*COUT + o
    const int b    = bo >> 5;
    const int o    = bo & 31;
    const int q    = qc * QPB + wid;

    // ---- Stage 0: trig tables + y into LDS
    if (tid < NM * KG) {
        ((float*)ca1s)[tid] = ca1[tid];
        ((float*)cg1s)[tid] = cg1[tid];
        ((float*)ca2s)[tid] = ca2[tid];
        ((float*)cg2s)[tid] = cg2[tid];
    }
    if (tid < TOTAL) {
        const float* xp = x + b * CIN * TOTAL + tid;
        const float* wp = w + o * CIN * TOTAL + tid;
        float acc = 0.f;
        #pragma unroll
        for (int c = 0; c < CIN; ++c)
            acc = fmaf(xp[c * TOTAL], wp[c * TOTAL], acc);
        ySm[tid] = acc;
    }
    __syncthreads();

    // ---- Stage A: S1[m,n] = sum_l y[i(l,m,n)]*d1[q,i], S2 likewise. 121 entries/wave.
    {
        const float* d1q = d1 + q * TOTAL;
        const float* d2q = d2 + q * TOTAL;
        for (int e = lane; e < NM * NM; e += 64) {
            const int mm = e / NM;
            const int nn = e - mm * NM;
            const int mp  = mm - (LB - 1);
            const int np_ = nn - (LB - 1);
            const int am = mp < 0 ? -mp : mp;
            const int an = np_ < 0 ? -np_ : np_;
            const int lmin = am > an ? am : an;
            float a1 = 0.f, a2 = 0.f;
            for (int l = lmin; l < LB; ++l) {
                const int i = l * (4 * l * l - 1) / 3 + (2 * l + 1) * (l + mp) + (l + np_);
                const float yv = ySm[i];
                a1 = fmaf(yv, d1q[i], a1);
                a2 = fmaf(yv, d2q[i], a2);
            }
            s1w[wid][e] = a1;
            s2w[wid][e] = a2;
        }
    }
    __syncthreads();

    // ---- Stage B: T{1,2}[m, r0..r0+3] via float4. 176 tasks/wave (t1:0..87, t2:88..175).
    for (int t = lane; t < 176; t += 64) {
        const int which = t >= 88;
        const int u = which ? t - 88 : t;
        const int m = u >> 3;
        const int r0 = (u & 7) << 2;
        const float* sp = which ? s2w[wid] : s1w[wid];
        const float(*cg)[KG] = which ? cg2s : cg1s;
        v4 acc = {0.f, 0.f, 0.f, 0.f};
        #pragma unroll
        for (int n = 0; n < NM; ++n) {
            const float s = sp[m * NM + n];
            const v4 cv = *(const v4*)&cg[n][r0];
            acc += s * cv;
        }
        float* tp = which ? &t2w[wid][m][r0] : &t1w[wid][m][r0];
        *(v4*)tp = acc;
    }
    __syncthreads();

    // ---- Stage C: resp[p,r] = sum_m ca1[m,p]*T1[m,r] + ca2[m,p]*T2[m,r].
    // Each lane owns a 4x4 (p,r) tile: 8x8 tiles = 64 lanes. Rank-1 updates, all b128 reads.
    float lmax = -INFINITY;
    {
        const int p0 = ((lane >> 3) & 7) << 2;
        const int r0 = (lane & 7) << 2;
        v4 acc0 = {0.f, 0.f, 0.f, 0.f};
        v4 acc1 = acc0, acc2 = acc0, acc3 = acc0;
        #pragma unroll
        for (int m = 0; m < NM; ++m) {
            const v4 c1 = *(const v4*)&ca1s[m][p0];
            const v4 c2 = *(const v4*)&ca2s[m][p0];
            const v4 v1 = *(const v4*)&t1w[wid][m][r0];
            const v4 v2 = *(const v4*)&t2w[wid][m][r0];
            acc0 += c1[0] * v1 + c2[0] * v2;
            acc1 += c1[1] * v1 + c2[1] * v2;
            acc2 += c1[2] * v1 + c2[2] * v2;
            acc3 += c1[3] * v1 + c2[3] * v2;
        }
        #pragma unroll
        for (int j = 0; j < 4; ++j) {
            lmax = fmaxf(lmax, acc0[j]);
            lmax = fmaxf(lmax, acc1[j]);
            lmax = fmaxf(lmax, acc2[j]);
            lmax = fmaxf(lmax, acc3[j]);
        }
    }

    // ---- Reduce: wave shuffle max, then across the 8 waves.
    #pragma unroll
    for (int off = 32; off > 0; off >>= 1)
        lmax = fmaxf(lmax, __shfl_xor(lmax, off, 64));
    if (lane == 0) redw[wid] = lmax;
    __syncthreads();
    if (tid == 0) {
        float v = redw[0];
        #pragma unroll
        for (int i = 1; i < QPB; ++i) v = fmaxf(v, redw[i]);
        partial[bid] = v;
    }
}

__global__ void so3_reduce(const float* __restrict__ partial, float* __restrict__ out) {
    const int t = threadIdx.x;
    if (t < BB * COUT) {
        float v = partial[t * QC];
        #pragma unroll
        for (int j = 1; j < QC; ++j) v = fmaxf(v, partial[t * QC + j]);
        out[t] = v;
    }
}

extern "C" void kernel_launch(void* const* d_in, const int* in_sizes, int n_in,
                              void* d_out, int out_size, void* d_ws, size_t ws_size,
                              hipStream_t stream) {
    const float* x   = (const float*)d_in[0];
    const float* w   = (const float*)d_in[1];
    const float* d1  = (const float*)d_in[2];
    const float* d2  = (const float*)d_in[3];
    const float* ca1 = (const float*)d_in[4];
    const float* cg1 = (const float*)d_in[5];
    const float* ca2 = (const float*)d_in[6];
    const float* cg2 = (const float*)d_in[7];
    float* partial = (float*)d_ws;   // B*COUT*QC = 1024 floats

    so3_main<<<BB * COUT * QC, 512, 0, stream>>>(x, w, d1, d2, ca1, cg1, ca2, cg2, partial);
    so3_reduce<<<1, 256, 0, stream>>>(partial, (float*)d_out);
}